// Round 6
// baseline (1957.713 us; speedup 1.0000x reference)
//
#include <hip/hip_runtime.h>

// QuantizedLinear: out[b,s,o] = sum_k x[b,s,k] * qw[o,k]
// qw in {-2,-1,0,1,2}/(9*alpha) -> single-plane bf16 MFMA GEMM.
// M=16384, N=4096, K=4096. fp32 in/out.
//
// R6: R5 geometry (256x256, BK=64, A triple-buf + B double-buf = 160 KiB,
//   one vmcnt(4)+barrier per K-tile) plus:
//   (a) SIMD-mate anti-phasing: wm=1 waves (SIMD-mates of wm=0) run each
//       tile's phases KS=1 first, so one wave's ds_read drain overlaps the
//       mate's MFMA cluster. Staging remains positional (issue order
//       B(t+1)h0,h1 then A(t+2)h0,h1) so per-wave vmcnt(4) semantics are
//       identical for both orders.
//   (b) No hand lgkmcnt(0) gates: compiler emits per-MFMA counted lgkmcnt,
//       releasing MFMAs as fragments land. Tile-end sched_barrier(0)+
//       vmcnt(4)+s_barrier still pins cross-tile ordering; all tile-t
//       ds_reads are consumed by tile-t MFMAs, so they are complete before
//       the wave crosses the barrier.
// Prepasses: K-chunk XOR pre-swizzled global layout -> linear global_load_lds
// + swizzled ds_read_b128 (0 bank conflicts measured).

typedef unsigned short u16;
typedef unsigned int u32;
typedef __bf16 bf16x8 __attribute__((ext_vector_type(8)));
typedef float f32x4 __attribute__((ext_vector_type(4)));

#define MDIM 16384
#define NDIM 4096
#define KDIM 4096

// ---------- helpers ----------

__device__ __forceinline__ u16 f2bf(float x) {
  u32 u = __float_as_uint(x);
  return (u16)((u + 0x7FFFu + ((u >> 16) & 1u)) >> 16);
}

__device__ __forceinline__ float quant_wint(float w, float alpha) {
  // nearest of {3.5,4.0,4.5,5.0,5.5} to 4.5*(1+w*alpha); argmin tie -> lower level.
  float tv = 4.5f * (1.0f + w * alpha);
  float u = (tv - 3.5f) * 2.0f;
  float f = ceilf(u - 0.5f);
  f = fminf(fmaxf(f, 0.0f), 4.0f);
  return f - 2.0f;                  // Wint in {-2..2}; scale 1/(9*alpha) in epilogue
}

__device__ __forceinline__ void gld16(const void* g, void* l) {
  __builtin_amdgcn_global_load_lds(
      (const __attribute__((address_space(1))) void*)g,
      (__attribute__((address_space(3))) void*)l, 16, 0, 0);
}

// ---------- prepass: quantize weight, swizzled store ----------

__global__ void quant_w_kernel(const float4* __restrict__ W,
                               const float* __restrict__ pAlpha,
                               u16* __restrict__ Wq) {
  float alpha = pAlpha[0];
  u32 g = blockIdx.x * 256u + threadIdx.x;
  u32 n = g >> 9, bw = g & 511u;
  u32 dbw = (bw & ~7u) | ((bw & 7u) ^ (n & 7u));
  float4 a = W[(size_t)g * 2];
  float4 b = W[(size_t)g * 2 + 1];
  float v[8] = {a.x, a.y, a.z, a.w, b.x, b.y, b.z, b.w};
  u32 o[4];
#pragma unroll
  for (int p = 0; p < 4; ++p) {
    u16 l0 = f2bf(quant_wint(v[2 * p], alpha));
    u16 l1 = f2bf(quant_wint(v[2 * p + 1], alpha));
    o[p] = (u32)l0 | ((u32)l1 << 16);
  }
  *(uint4*)&Wq[(size_t)n * 4096 + (size_t)dbw * 8] = make_uint4(o[0], o[1], o[2], o[3]);
}

// ---------- prepass: x -> bf16, swizzled store ----------

__global__ void cvt_x_kernel(const float4* __restrict__ X, u16* __restrict__ Xh) {
  u32 g = blockIdx.x * 256u + threadIdx.x;
  u32 m = g >> 9, bw = g & 511u;
  u32 dbw = (bw & ~7u) | ((bw & 7u) ^ (m & 7u));
  float4 a = X[(size_t)g * 2];
  float4 b = X[(size_t)g * 2 + 1];
  float v[8] = {a.x, a.y, a.z, a.w, b.x, b.y, b.z, b.w};
  u32 oh[4];
#pragma unroll
  for (int p = 0; p < 4; ++p) {
    u16 h0 = f2bf(v[2 * p]);
    u16 h1 = f2bf(v[2 * p + 1]);
    oh[p] = (u32)h0 | ((u32)h1 << 16);
  }
  *(uint4*)&Xh[(size_t)m * 4096 + (size_t)dbw * 8] = make_uint4(oh[0], oh[1], oh[2], oh[3]);
}

// ---------- main GEMM: 256x256, BK=64, anti-phased drift schedule ----------

#define BM 256
#define BN 256
#define BK 64
#define NKT (KDIM / BK)   // 64

// LDS byte map: Abuf p (p=0..2): p*32768 ; Bbuf q (q=0..1): 98304 + q*32768

__global__ __launch_bounds__(512, 2) void qgemm_kernel(
    const u16* __restrict__ Xh, const u16* __restrict__ Wq,
    const float* __restrict__ pAlpha, float* __restrict__ out) {
  __shared__ __align__(16) u16 sm[81920];   // 160 KiB
  const char* smb = (const char*)sm;

  const int t512 = threadIdx.x;
  const int lane = t512 & 63;
  const int wave = t512 >> 6;
  const int wm = wave >> 2;      // 0..1  (== SIMD-mate parity: wave i and i+4 share SIMD i)
  const int wn = wave & 3;       // 0..3

  // XCD-chunked swizzle: nwg=1024, 8 XCDs, 128 per chunk
  const int bid = blockIdx.x;
  const int nid = (bid & 7) * 128 + (bid >> 3);
  const int m_idx = nid >> 4;    // 64 M-tiles
  const int n_idx = nid & 15;    // 16 N-tiles (consecutive nid share A panel)
  const int m0 = m_idx * BM, n0 = n_idx * BN;

  const float alpha = pAlpha[0];

  f32x4 acc[8][4] = {};
  bf16x8 bfr[4];

  const int kb = (lane >> 4) << 4;     // byte offset of k-group within 128B row
  const int swz = (lane & 7) << 4;     // XOR swizzle (matches prepass layout)

  // frag row maps (interleaved across halves: mi>>2 / nj>>1 select the half)
#define AROW(MI) (wm * 64 + ((MI) >> 2) * 128 + ((MI)&3) * 16 + (lane & 15))
#define BROW(NJ) (wn * 32 + ((NJ) >> 1) * 128 + ((NJ)&1) * 16 + (lane & 15))
#define LDA(AB, MI, KS) \
  (*(const bf16x8*)(smb + (AB) + AROW(MI) * 128 + ((((KS)*64) + kb) ^ swz)))
#define LDB(BB, NJ, KS) \
  (*(const bf16x8*)(smb + (BB) + BROW(NJ) * 128 + ((((KS)*64) + kb) ^ swz)))

  // global row-block bases for half-tiles of k-tile KT (wrapped; junk tail
  // only ever lands in buffers that are never read again)
#define GA(KT, H) (Xh + (size_t)(m0 + (H)*128) * 4096 + (size_t)(((KT)&63)) * 64)
#define GB(KT, H) (Wq + (size_t)(n0 + (H)*128) * 4096 + (size_t)(((KT)&63)) * 64)

  // stage one 128x64 half-tile: 2 x global_load_lds(16B), linear dest
#define STAGE(GBASE, LELEM) do { \
    const u16* _g = (GBASE) + (size_t)(wave * 8 + (lane >> 3)) * 4096 + (size_t)((lane & 7) * 8); \
    gld16(_g, (void*)(sm + (LELEM) + wave * 512)); \
    gld16(_g + (size_t)64 * 4096, (void*)(sm + (LELEM) + 4096 + wave * 512)); \
  } while (0)

#define ACCROW(MI, AV) do { \
    acc[MI][0] = __builtin_amdgcn_mfma_f32_16x16x32_bf16(AV, bfr[0], acc[MI][0], 0, 0, 0); \
    acc[MI][1] = __builtin_amdgcn_mfma_f32_16x16x32_bf16(AV, bfr[1], acc[MI][1], 0, 0, 0); \
    acc[MI][2] = __builtin_amdgcn_mfma_f32_16x16x32_bf16(AV, bfr[2], acc[MI][2], 0, 0, 0); \
    acc[MI][3] = __builtin_amdgcn_mfma_f32_16x16x32_bf16(AV, bfr[3], acc[MI][3], 0, 0, 0); \
  } while (0)

  // phase: reads + 1 half-tile stage + 16 MFMA. No hand waitcnt gates:
  // compiler emits counted lgkmcnt per MFMA operand (fine-grained release).
#define PHASE(AB, BB, KS, MH, READB, SG, SL) do { \
    if (READB) { \
      bfr[0] = LDB(BB, 0, KS); bfr[1] = LDB(BB, 1, KS); \
      bfr[2] = LDB(BB, 2, KS); bfr[3] = LDB(BB, 3, KS); \
    } \
    bf16x8 a0 = LDA(AB, (MH)*4 + 0, KS); \
    bf16x8 a1 = LDA(AB, (MH)*4 + 1, KS); \
    bf16x8 a2 = LDA(AB, (MH)*4 + 2, KS); \
    bf16x8 a3 = LDA(AB, (MH)*4 + 3, KS); \
    STAGE(SG, SL); \
    __builtin_amdgcn_s_setprio(1); \
    ACCROW((MH)*4 + 0, a0); ACCROW((MH)*4 + 1, a1); \
    ACCROW((MH)*4 + 2, a2); ACCROW((MH)*4 + 3, a3); \
    __builtin_amdgcn_s_setprio(0); \
  } while (0)

  // one K-tile: 4 phases; wm=1 waves (SIMD-mates) run KS=1 first so their
  // MFMA clusters cover wm=0 waves' ds_read drains and vice versa.
  // Staging is positional: SG0/SL0..SG3/SL3 issued in that order by BOTH
  // variants (keeps per-wave vmcnt(4) invariant identical).
#define KTILE(AB, BB, SG0, SL0, SG1, SL1, SG2, SL2, SG3, SL3) do { \
    if (wm == 0) { \
      PHASE(AB, BB, 0, 0, 1, SG0, SL0); \
      PHASE(AB, BB, 0, 1, 0, SG1, SL1); \
      PHASE(AB, BB, 1, 0, 1, SG2, SL2); \
      PHASE(AB, BB, 1, 1, 0, SG3, SL3); \
    } else { \
      PHASE(AB, BB, 1, 0, 1, SG0, SL0); \
      PHASE(AB, BB, 1, 1, 0, SG1, SL1); \
      PHASE(AB, BB, 0, 0, 1, SG2, SL2); \
      PHASE(AB, BB, 0, 1, 0, SG3, SL3); \
    } \
  } while (0)

#define TILEGATE do { \
    __builtin_amdgcn_sched_barrier(0); \
    asm volatile("s_waitcnt vmcnt(4)" ::: "memory"); \
    __builtin_amdgcn_s_barrier(); \
    __builtin_amdgcn_sched_barrier(0); \
  } while (0)

  // prologue: B(0)->Bbuf0, A(0)->Abuf0, A(1)->Abuf1 (12 loads);
  // vm4 leaves A(1) in flight = steady state.
  STAGE(GB(0, 0), 49152);
  STAGE(GB(0, 1), 49152 + 8192);
  STAGE(GA(0, 0), 0);
  STAGE(GA(0, 1), 8192);
  STAGE(GA(1, 0), 16384);
  STAGE(GA(1, 1), 16384 + 8192);
  asm volatile("s_waitcnt vmcnt(4)" ::: "memory");
  __builtin_amdgcn_s_barrier();
  __builtin_amdgcn_sched_barrier(0);

  // rotating A-buffer byte bases: cur, nxt, stage-target (t+2)
  int aC = 0, aN = 32768, aS = 65536;

#pragma unroll 1
  for (int t = 0; t < NKT; t += 2) {
    const int aCe = aC >> 1, aSe = aS >> 1;   // element offsets
    // tile t: reads Abuf aC + Bbuf0; stages B(t+1)->Bbuf1, A(t+2)->Abuf aS
    KTILE(aC, 98304,
          GB(t + 1, 0), 65536, GB(t + 1, 1), 65536 + 8192,
          GA(t + 2, 0), aSe, GA(t + 2, 1), aSe + 8192);
    TILEGATE;   // A(t+1),B(t+1) landed; A(t+2) in flight
    // tile t+1: reads Abuf aN + Bbuf1; stages B(t+2)->Bbuf0, A(t+3)->Abuf aC
    KTILE(aN, 131072,
          GB(t + 2, 0), 49152, GB(t + 2, 1), 49152 + 8192,
          GA(t + 3, 0), aCe, GA(t + 3, 1), aCe + 8192);
    TILEGATE;   // A(t+2),B(t+2) landed; A(t+3) in flight
    // rotate: new (cur,nxt,st2) = (st2,cur,nxt)
    int tmp = aC; aC = aS; aS = aN; aN = tmp;
  }

  // epilogue
  const float scale = 1.0f / (9.0f * alpha);
#pragma unroll
  for (int mi = 0; mi < 8; ++mi) {
    int row = m0 + (mi >> 2) * 128 + wm * 64 + (mi & 3) * 16 + (lane >> 4) * 4;
#pragma unroll
    for (int nj = 0; nj < 4; ++nj) {
      int col = n0 + (nj >> 1) * 128 + wn * 32 + (nj & 1) * 16 + (lane & 15);
#pragma unroll
      for (int r = 0; r < 4; ++r)
        out[(size_t)(row + r) * NDIM + col] = acc[mi][nj][r] * scale;
    }
  }
#undef TILEGATE
#undef KTILE
#undef PHASE
#undef ACCROW
#undef STAGE
#undef GA
#undef GB
#undef LDA
#undef LDB
#undef AROW
#undef BROW
}

// ---------- fallback (ws too small): fp32 tiled GEMM, quant on the fly ----------

__global__ void fb_gemm_kernel(const float* __restrict__ X, const float* __restrict__ W,
                               const float* __restrict__ pAlpha, float* __restrict__ out) {
  __shared__ float As[64][17];
  __shared__ float Ws[64][17];
  const float alpha = pAlpha[0];
  const float scale = 1.0f / (9.0f * alpha);
  const int bm = blockIdx.x >> 6, bn = blockIdx.x & 63;
  const int t = threadIdx.x;
  const int tx = t & 15, ty = t >> 4;
  float acc[4][4] = {};
  for (int k0 = 0; k0 < KDIM; k0 += 16) {
    int r = t >> 2;
#pragma unroll
    for (int i = 0; i < 4; ++i) {
      int c = (t & 3) * 4 + i;
      As[r][c] = X[(size_t)(bm * 64 + r) * KDIM + k0 + c];
      float w = W[(size_t)(bn * 64 + r) * KDIM + k0 + c];
      Ws[r][c] = quant_wint(w, alpha) * scale;
    }
    __syncthreads();
#pragma unroll
    for (int kk = 0; kk < 16; ++kk)
#pragma unroll
      for (int i = 0; i < 4; ++i)
#pragma unroll
        for (int j = 0; j < 4; ++j)
          acc[i][j] += As[ty * 4 + i][kk] * Ws[tx * 4 + j][kk];
    __syncthreads();
  }
#pragma unroll
  for (int i = 0; i < 4; ++i)
#pragma unroll
    for (int j = 0; j < 4; ++j)
      out[(size_t)(bm * 64 + ty * 4 + i) * NDIM + bn * 64 + tx * 4 + j] = acc[i][j];
}

// ---------- launch ----------

extern "C" void kernel_launch(void* const* d_in, const int* in_sizes, int n_in,
                              void* d_out, int out_size, void* d_ws, size_t ws_size,
                              hipStream_t stream) {
  const float* x = (const float*)d_in[0];       // [16384,4096]
  const float* w = (const float*)d_in[1];       // [4096,4096]
  const float* alpha = (const float*)d_in[2];   // scalar
  float* out = (float*)d_out;

  const size_t WQ_BYTES = (size_t)NDIM * KDIM * 2;          // 33.5 MB
  const size_t XP_BYTES = (size_t)MDIM * KDIM * 2;          // 134 MB
  const size_t NEED = WQ_BYTES + XP_BYTES;                  // ~168 MB

  if (ws_size >= NEED) {
    u16* Wq = (u16*)d_ws;
    u16* Xh = (u16*)((char*)d_ws + WQ_BYTES);
    quant_w_kernel<<<(NDIM * KDIM / 8) / 256, 256, 0, stream>>>(
        (const float4*)w, alpha, Wq);
    cvt_x_kernel<<<(MDIM * KDIM / 8) / 256, 256, 0, stream>>>(
        (const float4*)x, Xh);
    qgemm_kernel<<<(MDIM / BM) * (NDIM / BN), 512, 0, stream>>>(
        Xh, Wq, alpha, out);
  } else {
    fb_gemm_kernel<<<(MDIM / 64) * (NDIM / 64), 256, 0, stream>>>(x, w, alpha, out);
  }
}

// Round 7
// 371.952 us; speedup vs baseline: 5.2633x; 5.2633x over previous
//
#include <hip/hip_runtime.h>

// QuantizedLinear: out[b,s,o] = sum_k x[b,s,k] * qw[o,k]
// qw = Wint/(9*alpha), Wint in {-2..2}  -> INT8 MFMA GEMM:
//   x quantized per-row to i8 (s_m = rowmax/127), W exact in i8,
//   i32 accumulation exact; epilogue scales by s_m/(9*alpha).
// M=16384, N=4096, K=4096. fp32 in/out.
//
// R7: i8 halves BOTH co-binding pipes of the R5 structure (MFMA cyc via
//   16x16x64 K-doubling; LDS bytes via 1B elems). Skeleton = R5 (proven):
//   256x256, BK=64, 4 phases/tile, per-phase lgkmcnt(0)+sched_barrier gates
//   (RESTORED - their removal in R6 caused scratch spill: WRITE_SIZE 2.5GB),
//   A triple-buf + B double-buf (80 KiB), one vmcnt(2)+barrier per tile,
//   positional staging, XCD-chunked block swizzle.
// Prepasses write the exact LDS image (row-major 64B rows, byte-col XOR
// ((row&3)<<4)) chunked per 256x64 tile -> linear global_load_lds + XOR'd
// ds_read is conflict-free (full-coverage permutation of each 1KB block).

typedef unsigned short u16;
typedef unsigned int u32;
typedef signed char s8;
typedef int v4i __attribute__((ext_vector_type(4)));

#define MDIM 16384
#define NDIM 4096
#define KDIM 4096

// ---------- helpers ----------

__device__ __forceinline__ float quant_wint(float w, float alpha) {
  // nearest of {3.5,4.0,4.5,5.0,5.5} to 4.5*(1+w*alpha); argmin tie -> lower level.
  float tv = 4.5f * (1.0f + w * alpha);
  float u = (tv - 3.5f) * 2.0f;
  float f = ceilf(u - 0.5f);
  f = fminf(fmaxf(f, 0.0f), 4.0f);
  return f - 2.0f;                  // Wint in {-2..2}; scale 1/(9*alpha) in epilogue
}

__device__ __forceinline__ void gld16(const void* g, void* l) {
  __builtin_amdgcn_global_load_lds(
      (const __attribute__((address_space(1))) void*)g,
      (__attribute__((address_space(3))) void*)l, 16, 0, 0);
}

__device__ __forceinline__ int q8(float x, float sinv) {
  float f = rintf(x * sinv);
  f = fminf(fmaxf(f, -127.0f), 127.0f);
  return (int)f;
}

// ---------- prepass: x -> per-row-scaled i8, chunked+swizzled image ----------
// chunk(mblk,kblk) = 16384B; image[r*64 + (c ^ ((r&3)<<4))] = xq[mblk*256+r][kblk*64+c]

__global__ __launch_bounds__(256) void quant_x_kernel(
    const float4* __restrict__ X, s8* __restrict__ Xq, float* __restrict__ scales) {
  const int m = blockIdx.x;        // 16384 rows
  const int t = threadIdx.x;       // 256 thr; thread t owns k in [t*16, t*16+16)
  const float4* row = X + (size_t)m * 1024;
  float4 v0 = row[t * 4 + 0], v1 = row[t * 4 + 1], v2 = row[t * 4 + 2], v3 = row[t * 4 + 3];
  float vals[16] = {v0.x, v0.y, v0.z, v0.w, v1.x, v1.y, v1.z, v1.w,
                    v2.x, v2.y, v2.z, v2.w, v3.x, v3.y, v3.z, v3.w};
  float mx = 0.0f;
#pragma unroll
  for (int j = 0; j < 16; ++j) mx = fmaxf(mx, fabsf(vals[j]));
#pragma unroll
  for (int s = 1; s < 64; s <<= 1) mx = fmaxf(mx, __shfl_xor(mx, s));
  __shared__ float red[4];
  if ((t & 63) == 0) red[t >> 6] = mx;
  __syncthreads();
  float rmax = fmaxf(fmaxf(red[0], red[1]), fmaxf(red[2], red[3]));
  float sinv = rmax > 0.0f ? 127.0f / rmax : 0.0f;
  if (t == 0) scales[m] = rmax * (1.0f / 127.0f);
  u32 pk[4];
#pragma unroll
  for (int p = 0; p < 4; ++p) {
    u32 w = 0;
#pragma unroll
    for (int j = 0; j < 4; ++j)
      w |= ((u32)(unsigned char)(signed char)q8(vals[p * 4 + j], sinv)) << (8 * j);
    pk[p] = w;
  }
  size_t chunk = ((size_t)(m >> 8) * 64 + (size_t)(t >> 2)) * 16384;
  u32 off = (u32)((m & 255) * 64 + ((((t & 3) ^ (m & 3)) << 4)));
  *(uint4*)(Xq + chunk + off) = make_uint4(pk[0], pk[1], pk[2], pk[3]);
}

// ---------- prepass: W -> Wint i8, chunked+swizzled image ----------

__global__ __launch_bounds__(256) void quant_w8_kernel(
    const float4* __restrict__ W, const float* __restrict__ pAlpha,
    s8* __restrict__ Wq) {
  const float alpha = pAlpha[0];
  const int n = blockIdx.x;        // 4096 rows
  const int t = threadIdx.x;
  const float4* row = W + (size_t)n * 1024;
  float4 v0 = row[t * 4 + 0], v1 = row[t * 4 + 1], v2 = row[t * 4 + 2], v3 = row[t * 4 + 3];
  float vals[16] = {v0.x, v0.y, v0.z, v0.w, v1.x, v1.y, v1.z, v1.w,
                    v2.x, v2.y, v2.z, v2.w, v3.x, v3.y, v3.z, v3.w};
  u32 pk[4];
#pragma unroll
  for (int p = 0; p < 4; ++p) {
    u32 w = 0;
#pragma unroll
    for (int j = 0; j < 4; ++j) {
      int q = (int)quant_wint(vals[p * 4 + j], alpha);   // -2..2 exact
      w |= ((u32)(unsigned char)(signed char)q) << (8 * j);
    }
    pk[p] = w;
  }
  size_t chunk = ((size_t)(n >> 8) * 64 + (size_t)(t >> 2)) * 16384;
  u32 off = (u32)((n & 255) * 64 + ((((t & 3) ^ (n & 3)) << 4)));
  *(uint4*)(Wq + chunk + off) = make_uint4(pk[0], pk[1], pk[2], pk[3]);
}

// ---------- main GEMM: 256x256, BK=64, i8, R5 drift schedule ----------

#define BM 256
#define BN 256
#define BK 64
#define NKT (KDIM / BK)   // 64

// LDS byte map: Abuf p (0..2): p*16384 ; Bbuf q (0..1): 49152 + q*16384  = 80 KiB

__global__ __launch_bounds__(512, 2) void qgemm_kernel(
    const s8* __restrict__ Xq, const s8* __restrict__ Wq,
    const float* __restrict__ scales, const float* __restrict__ pAlpha,
    float* __restrict__ out) {
  __shared__ __align__(16) char sm8[81920];

  const int t512 = threadIdx.x;
  const int lane = t512 & 63;
  const int wave = t512 >> 6;
  const int wm = wave >> 2;      // 0..1
  const int wn = wave & 3;       // 0..3

  // XCD-chunked swizzle: nwg=1024, 8 XCDs, 128 per chunk
  const int bid = blockIdx.x;
  const int nid = (bid & 7) * 128 + (bid >> 3);
  const int m_idx = nid >> 4;    // 64 M-tiles
  const int n_idx = nid & 15;    // 16 N-tiles (consecutive nid share A panel)
  const int m0 = m_idx * BM, n0 = n_idx * BN;

  const float alpha = pAlpha[0];

  v4i acc[8][4] = {};
  v4i bfr[4];

  // read byte-offset within a 64B row: k-chunk (lane>>4)*16, XOR'd by row&3
  // (row = ... + (lane&15) so row&3 == lane&3)
  const int koff = (((lane >> 4) ^ (lane & 3)) << 4);

#define AROW(MI) (wm * 64 + ((MI) >> 2) * 128 + ((MI)&3) * 16 + (lane & 15))
#define BROW(NJ) (wn * 32 + ((NJ) >> 1) * 128 + ((NJ)&1) * 16 + (lane & 15))
#define LDA(AB, MI) (*(const v4i*)(sm8 + (AB) + AROW(MI) * 64 + koff))
#define LDB(BB, NJ) (*(const v4i*)(sm8 + (BB) + BROW(NJ) * 64 + koff))

  // chunk bases (16 KiB per 256x64 operand tile; KT wraps, junk tail lands
  // only in buffers that are never read again)
#define GAC(KT) (Xq + ((size_t)m_idx * 64 + (size_t)((KT)&63)) * 16384)
#define GBC(KT) (Wq + ((size_t)n_idx * 64 + (size_t)((KT)&63)) * 16384)

  // stage one 8KB sweep (S=0/1) of a 16KB tile: 1 gld16/thread, linear dest
#define STAGE(GC, S, LB) do { \
    const s8* _g = (GC) + (S)*8192 + wave * 1024 + lane * 16; \
    gld16(_g, (void*)(sm8 + (LB) + (S)*8192 + wave * 1024)); \
  } while (0)

#define MFMA8(MI0, MI1, A0, A1) do { \
    acc[MI0][0] = __builtin_amdgcn_mfma_i32_16x16x64_i8(A0, bfr[0], acc[MI0][0], 0, 0, 0); \
    acc[MI0][1] = __builtin_amdgcn_mfma_i32_16x16x64_i8(A0, bfr[1], acc[MI0][1], 0, 0, 0); \
    acc[MI0][2] = __builtin_amdgcn_mfma_i32_16x16x64_i8(A0, bfr[2], acc[MI0][2], 0, 0, 0); \
    acc[MI0][3] = __builtin_amdgcn_mfma_i32_16x16x64_i8(A0, bfr[3], acc[MI0][3], 0, 0, 0); \
    acc[MI1][0] = __builtin_amdgcn_mfma_i32_16x16x64_i8(A1, bfr[0], acc[MI1][0], 0, 0, 0); \
    acc[MI1][1] = __builtin_amdgcn_mfma_i32_16x16x64_i8(A1, bfr[1], acc[MI1][1], 0, 0, 0); \
    acc[MI1][2] = __builtin_amdgcn_mfma_i32_16x16x64_i8(A1, bfr[2], acc[MI1][2], 0, 0, 0); \
    acc[MI1][3] = __builtin_amdgcn_mfma_i32_16x16x64_i8(A1, bfr[3], acc[MI1][3], 0, 0, 0); \
  } while (0)

  // phase: {ds_read 2 A-frags (+4 B-frags in ph0); stage 1 sweep} ->
  //        lgkm(0) gate (bounds live ranges - R6 lesson) -> 8 MFMA
#define PHASE(AB, MI0, MI1, READB, BB, SGC, SS, SLB) do { \
    if (READB) { \
      bfr[0] = LDB(BB, 0); bfr[1] = LDB(BB, 1); \
      bfr[2] = LDB(BB, 2); bfr[3] = LDB(BB, 3); \
    } \
    v4i a0 = LDA(AB, MI0); \
    v4i a1 = LDA(AB, MI1); \
    STAGE(SGC, SS, SLB); \
    __builtin_amdgcn_sched_barrier(0); \
    asm volatile("s_waitcnt lgkmcnt(0)" ::: "memory"); \
    __builtin_amdgcn_sched_barrier(0); \
    __builtin_amdgcn_s_setprio(1); \
    MFMA8(MI0, MI1, a0, a1); \
    __builtin_amdgcn_s_setprio(0); \
  } while (0)

#define TILEGATE do { \
    __builtin_amdgcn_sched_barrier(0); \
    asm volatile("s_waitcnt vmcnt(2)" ::: "memory"); \
    __builtin_amdgcn_s_barrier(); \
    __builtin_amdgcn_sched_barrier(0); \
  } while (0)

  // one K-tile: 4 phases; stages (positional): B(t+1)s0, B(t+1)s1,
  // A(t+2)s0, A(t+2)s1 -> tile-end vmcnt(2) leaves A(t+2) in flight.
#define KTILE(AB, BB, BBN, ASB, TT) do { \
    PHASE(AB, 0, 1, 1, BB, GBC((TT) + 1), 0, BBN); \
    PHASE(AB, 2, 3, 0, BB, GBC((TT) + 1), 1, BBN); \
    PHASE(AB, 4, 5, 0, BB, GAC((TT) + 2), 0, ASB); \
    PHASE(AB, 6, 7, 0, BB, GAC((TT) + 2), 1, ASB); \
    TILEGATE; \
  } while (0)

  // prologue: B(0)->Bbuf0, A(0)->Abuf0, A(1)->Abuf1; vm2 leaves A(1) in flight
  STAGE(GBC(0), 0, 49152);
  STAGE(GBC(0), 1, 49152);
  STAGE(GAC(0), 0, 0);
  STAGE(GAC(0), 1, 0);
  STAGE(GAC(1), 0, 16384);
  STAGE(GAC(1), 1, 16384);
  asm volatile("s_waitcnt vmcnt(2)" ::: "memory");
  __builtin_amdgcn_s_barrier();
  __builtin_amdgcn_sched_barrier(0);

  int aC = 0, aN = 16384, aS = 32768;

#pragma unroll 1
  for (int t = 0; t < NKT; t += 2) {
    // tile t: A in aC, B in Bbuf0; stage B(t+1)->Bbuf1, A(t+2)->aS
    KTILE(aC, 49152, 65536, aS, t);
    // tile t+1: A in aN, B in Bbuf1; stage B(t+2)->Bbuf0, A(t+3)->aC
    KTILE(aN, 65536, 49152, aC, t + 1);
    int tmp = aC; aC = aS; aS = aN; aN = tmp;
  }

  // epilogue: out = acc_i32 * scales[row] / (9*alpha)
  const float inv9a = 1.0f / (9.0f * alpha);
#pragma unroll
  for (int mi = 0; mi < 8; ++mi) {
    int rbase = m0 + (mi >> 2) * 128 + wm * 64 + (mi & 3) * 16 + (lane >> 4) * 4;
    float s0 = scales[rbase + 0] * inv9a;
    float s1 = scales[rbase + 1] * inv9a;
    float s2 = scales[rbase + 2] * inv9a;
    float s3 = scales[rbase + 3] * inv9a;
#pragma unroll
    for (int nj = 0; nj < 4; ++nj) {
      int col = n0 + (nj >> 1) * 128 + wn * 32 + (nj & 1) * 16 + (lane & 15);
      out[(size_t)(rbase + 0) * NDIM + col] = (float)acc[mi][nj][0] * s0;
      out[(size_t)(rbase + 1) * NDIM + col] = (float)acc[mi][nj][1] * s1;
      out[(size_t)(rbase + 2) * NDIM + col] = (float)acc[mi][nj][2] * s2;
      out[(size_t)(rbase + 3) * NDIM + col] = (float)acc[mi][nj][3] * s3;
    }
  }
#undef KTILE
#undef TILEGATE
#undef PHASE
#undef MFMA8
#undef STAGE
#undef GAC
#undef GBC
#undef LDA
#undef LDB
#undef AROW
#undef BROW
}

// ---------- fallback (ws too small): fp32 tiled GEMM, quant on the fly ----------

__global__ void fb_gemm_kernel(const float* __restrict__ X, const float* __restrict__ W,
                               const float* __restrict__ pAlpha, float* __restrict__ out) {
  __shared__ float As[64][17];
  __shared__ float Ws[64][17];
  const float alpha = pAlpha[0];
  const float scale = 1.0f / (9.0f * alpha);
  const int bm = blockIdx.x >> 6, bn = blockIdx.x & 63;
  const int t = threadIdx.x;
  const int tx = t & 15, ty = t >> 4;
  float acc[4][4] = {};
  for (int k0 = 0; k0 < KDIM; k0 += 16) {
    int r = t >> 2;
#pragma unroll
    for (int i = 0; i < 4; ++i) {
      int c = (t & 3) * 4 + i;
      As[r][c] = X[(size_t)(bm * 64 + r) * KDIM + k0 + c];
      float w = W[(size_t)(bn * 64 + r) * KDIM + k0 + c];
      Ws[r][c] = quant_wint(w, alpha) * scale;
    }
    __syncthreads();
#pragma unroll
    for (int kk = 0; kk < 16; ++kk)
#pragma unroll
      for (int i = 0; i < 4; ++i)
#pragma unroll
        for (int j = 0; j < 4; ++j)
          acc[i][j] += As[ty * 4 + i][kk] * Ws[tx * 4 + j][kk];
    __syncthreads();
  }
#pragma unroll
  for (int i = 0; i < 4; ++i)
#pragma unroll
    for (int j = 0; j < 4; ++j)
      out[(size_t)(bm * 64 + ty * 4 + i) * NDIM + bn * 64 + tx * 4 + j] = acc[i][j];
}

// ---------- launch ----------

extern "C" void kernel_launch(void* const* d_in, const int* in_sizes, int n_in,
                              void* d_out, int out_size, void* d_ws, size_t ws_size,
                              hipStream_t stream) {
  const float* x = (const float*)d_in[0];       // [16384,4096]
  const float* w = (const float*)d_in[1];       // [4096,4096]
  const float* alpha = (const float*)d_in[2];   // scalar
  float* out = (float*)d_out;

  const size_t XQ_BYTES = (size_t)MDIM * KDIM;              // 67.1 MB
  const size_t WQ_BYTES = (size_t)NDIM * KDIM;              // 16.8 MB
  const size_t SC_BYTES = (size_t)MDIM * 4;                 // 64 KB
  const size_t NEED = XQ_BYTES + WQ_BYTES + SC_BYTES;       // ~84 MB

  if (ws_size >= NEED) {
    s8* Xq = (s8*)d_ws;
    s8* Wq = (s8*)((char*)d_ws + XQ_BYTES);
    float* scales = (float*)((char*)d_ws + XQ_BYTES + WQ_BYTES);
    quant_x_kernel<<<MDIM, 256, 0, stream>>>((const float4*)x, Xq, scales);
    quant_w8_kernel<<<NDIM, 256, 0, stream>>>((const float4*)w, alpha, Wq);
    qgemm_kernel<<<(MDIM / BM) * (NDIM / BN), 512, 0, stream>>>(
        Xq, Wq, scales, alpha, out);
  } else {
    fb_gemm_kernel<<<(MDIM / 64) * (NDIM / 64), 256, 0, stream>>>(x, w, alpha, out);
  }
}

// Round 8
// 362.977 us; speedup vs baseline: 5.3935x; 1.0247x over previous
//
#include <hip/hip_runtime.h>

// QuantizedLinear: out[b,s,o] = sum_k x[b,s,k] * qw[o,k]
// qw = Wint/(9*alpha), Wint in {-2..2}  -> INT8 MFMA GEMM:
//   x quantized per-row to i8 (s_m = rowmax/127), W exact in i8,
//   i32 accumulation exact; epilogue scales by s_m/(9*alpha).
// M=16384, N=4096, K=4096. fp32 in/out.
//
// R8: fix i8 LDS bank conflicts (R7: 2.5e7 conflicts, 4-way). 64B rows have
//   4 slots; old XOR (r&3) gave bank-set period 4 in r (set = (r&1)<<2 |
//   (c^(r&3))). New XOR ((r>>1)&3): set = (r&1)<<2 | (c^((r>>1)&3)) covers
//   all 8 sets over r=0..7 -> 16 consecutive rows = 2 lanes/set (free).
//   Lane->slot stays bijective per row -> full-coverage permutation like the
//   0-conflict bf16 layout. Changed in both prepass images + GEMM koff only.
// Skeleton = R7/R5: 256x256, BK=64, 4 phases/tile, per-phase lgkmcnt(0)+
//   sched_barrier gates (bound live ranges - R6 spill lesson), A triple-buf +
//   B double-buf (80 KiB), one vmcnt(2)+barrier per tile, positional staging,
//   XCD-chunked block swizzle.

typedef unsigned short u16;
typedef unsigned int u32;
typedef signed char s8;
typedef int v4i __attribute__((ext_vector_type(4)));

#define MDIM 16384
#define NDIM 4096
#define KDIM 4096

// ---------- helpers ----------

__device__ __forceinline__ float quant_wint(float w, float alpha) {
  // nearest of {3.5,4.0,4.5,5.0,5.5} to 4.5*(1+w*alpha); argmin tie -> lower level.
  float tv = 4.5f * (1.0f + w * alpha);
  float u = (tv - 3.5f) * 2.0f;
  float f = ceilf(u - 0.5f);
  f = fminf(fmaxf(f, 0.0f), 4.0f);
  return f - 2.0f;                  // Wint in {-2..2}; scale 1/(9*alpha) in epilogue
}

__device__ __forceinline__ void gld16(const void* g, void* l) {
  __builtin_amdgcn_global_load_lds(
      (const __attribute__((address_space(1))) void*)g,
      (__attribute__((address_space(3))) void*)l, 16, 0, 0);
}

__device__ __forceinline__ int q8(float x, float sinv) {
  float f = rintf(x * sinv);
  f = fminf(fmaxf(f, -127.0f), 127.0f);
  return (int)f;
}

// ---------- prepass: x -> per-row-scaled i8, chunked+swizzled image ----------
// chunk(mblk,kblk) = 16384B; image[r*64 + (c ^ (((r>>1)&3)<<4))] (c = 16B slot)

__global__ __launch_bounds__(256) void quant_x_kernel(
    const float4* __restrict__ X, s8* __restrict__ Xq, float* __restrict__ scales) {
  const int m = blockIdx.x;        // 16384 rows
  const int t = threadIdx.x;       // 256 thr; thread t owns k in [t*16, t*16+16)
  const float4* row = X + (size_t)m * 1024;
  float4 v0 = row[t * 4 + 0], v1 = row[t * 4 + 1], v2 = row[t * 4 + 2], v3 = row[t * 4 + 3];
  float vals[16] = {v0.x, v0.y, v0.z, v0.w, v1.x, v1.y, v1.z, v1.w,
                    v2.x, v2.y, v2.z, v2.w, v3.x, v3.y, v3.z, v3.w};
  float mx = 0.0f;
#pragma unroll
  for (int j = 0; j < 16; ++j) mx = fmaxf(mx, fabsf(vals[j]));
#pragma unroll
  for (int s = 1; s < 64; s <<= 1) mx = fmaxf(mx, __shfl_xor(mx, s));
  __shared__ float red[4];
  if ((t & 63) == 0) red[t >> 6] = mx;
  __syncthreads();
  float rmax = fmaxf(fmaxf(red[0], red[1]), fmaxf(red[2], red[3]));
  float sinv = rmax > 0.0f ? 127.0f / rmax : 0.0f;
  if (t == 0) scales[m] = rmax * (1.0f / 127.0f);
  u32 pk[4];
#pragma unroll
  for (int p = 0; p < 4; ++p) {
    u32 w = 0;
#pragma unroll
    for (int j = 0; j < 4; ++j)
      w |= ((u32)(unsigned char)(signed char)q8(vals[p * 4 + j], sinv)) << (8 * j);
    pk[p] = w;
  }
  size_t chunk = ((size_t)(m >> 8) * 64 + (size_t)(t >> 2)) * 16384;
  u32 off = (u32)((m & 255) * 64 + ((((t & 3) ^ ((m >> 1) & 3)) << 4)));
  *(uint4*)(Xq + chunk + off) = make_uint4(pk[0], pk[1], pk[2], pk[3]);
}

// ---------- prepass: W -> Wint i8, chunked+swizzled image ----------

__global__ __launch_bounds__(256) void quant_w8_kernel(
    const float4* __restrict__ W, const float* __restrict__ pAlpha,
    s8* __restrict__ Wq) {
  const float alpha = pAlpha[0];
  const int n = blockIdx.x;        // 4096 rows
  const int t = threadIdx.x;
  const float4* row = W + (size_t)n * 1024;
  float4 v0 = row[t * 4 + 0], v1 = row[t * 4 + 1], v2 = row[t * 4 + 2], v3 = row[t * 4 + 3];
  float vals[16] = {v0.x, v0.y, v0.z, v0.w, v1.x, v1.y, v1.z, v1.w,
                    v2.x, v2.y, v2.z, v2.w, v3.x, v3.y, v3.z, v3.w};
  u32 pk[4];
#pragma unroll
  for (int p = 0; p < 4; ++p) {
    u32 w = 0;
#pragma unroll
    for (int j = 0; j < 4; ++j) {
      int q = (int)quant_wint(vals[p * 4 + j], alpha);   // -2..2 exact
      w |= ((u32)(unsigned char)(signed char)q) << (8 * j);
    }
    pk[p] = w;
  }
  size_t chunk = ((size_t)(n >> 8) * 64 + (size_t)(t >> 2)) * 16384;
  u32 off = (u32)((n & 255) * 64 + ((((t & 3) ^ ((n >> 1) & 3)) << 4)));
  *(uint4*)(Wq + chunk + off) = make_uint4(pk[0], pk[1], pk[2], pk[3]);
}

// ---------- main GEMM: 256x256, BK=64, i8, R5 drift schedule ----------

#define BM 256
#define BN 256
#define BK 64
#define NKT (KDIM / BK)   // 64

// LDS byte map: Abuf p (0..2): p*16384 ; Bbuf q (0..1): 49152 + q*16384  = 80 KiB

__global__ __launch_bounds__(512, 2) void qgemm_kernel(
    const s8* __restrict__ Xq, const s8* __restrict__ Wq,
    const float* __restrict__ scales, const float* __restrict__ pAlpha,
    float* __restrict__ out) {
  __shared__ __align__(16) char sm8[81920];

  const int t512 = threadIdx.x;
  const int lane = t512 & 63;
  const int wave = t512 >> 6;
  const int wm = wave >> 2;      // 0..1
  const int wn = wave & 3;       // 0..3

  // XCD-chunked swizzle: nwg=1024, 8 XCDs, 128 per chunk
  const int bid = blockIdx.x;
  const int nid = (bid & 7) * 128 + (bid >> 3);
  const int m_idx = nid >> 4;    // 64 M-tiles
  const int n_idx = nid & 15;    // 16 N-tiles (consecutive nid share A panel)
  const int m0 = m_idx * BM, n0 = n_idx * BN;

  const float alpha = pAlpha[0];

  v4i acc[8][4] = {};
  v4i bfr[4];

  // read byte-offset within a 64B row: k-slot (lane>>4), XOR'd by (row>>1)&3
  // (row = 16*k + (lane&15) -> (row>>1)&3 == (lane>>1)&3)
  const int koff = (((lane >> 4) ^ ((lane >> 1) & 3)) << 4);

#define AROW(MI) (wm * 64 + ((MI) >> 2) * 128 + ((MI)&3) * 16 + (lane & 15))
#define BROW(NJ) (wn * 32 + ((NJ) >> 1) * 128 + ((NJ)&1) * 16 + (lane & 15))
#define LDA(AB, MI) (*(const v4i*)(sm8 + (AB) + AROW(MI) * 64 + koff))
#define LDB(BB, NJ) (*(const v4i*)(sm8 + (BB) + BROW(NJ) * 64 + koff))

  // chunk bases (16 KiB per 256x64 operand tile; KT wraps, junk tail lands
  // only in buffers that are never read again)
#define GAC(KT) (Xq + ((size_t)m_idx * 64 + (size_t)((KT)&63)) * 16384)
#define GBC(KT) (Wq + ((size_t)n_idx * 64 + (size_t)((KT)&63)) * 16384)

  // stage one 8KB sweep (S=0/1) of a 16KB tile: 1 gld16/thread, linear dest
#define STAGE(GC, S, LB) do { \
    const s8* _g = (GC) + (S)*8192 + wave * 1024 + lane * 16; \
    gld16(_g, (void*)(sm8 + (LB) + (S)*8192 + wave * 1024)); \
  } while (0)

#define MFMA8(MI0, MI1, A0, A1) do { \
    acc[MI0][0] = __builtin_amdgcn_mfma_i32_16x16x64_i8(A0, bfr[0], acc[MI0][0], 0, 0, 0); \
    acc[MI0][1] = __builtin_amdgcn_mfma_i32_16x16x64_i8(A0, bfr[1], acc[MI0][1], 0, 0, 0); \
    acc[MI0][2] = __builtin_amdgcn_mfma_i32_16x16x64_i8(A0, bfr[2], acc[MI0][2], 0, 0, 0); \
    acc[MI0][3] = __builtin_amdgcn_mfma_i32_16x16x64_i8(A0, bfr[3], acc[MI0][3], 0, 0, 0); \
    acc[MI1][0] = __builtin_amdgcn_mfma_i32_16x16x64_i8(A1, bfr[0], acc[MI1][0], 0, 0, 0); \
    acc[MI1][1] = __builtin_amdgcn_mfma_i32_16x16x64_i8(A1, bfr[1], acc[MI1][1], 0, 0, 0); \
    acc[MI1][2] = __builtin_amdgcn_mfma_i32_16x16x64_i8(A1, bfr[2], acc[MI1][2], 0, 0, 0); \
    acc[MI1][3] = __builtin_amdgcn_mfma_i32_16x16x64_i8(A1, bfr[3], acc[MI1][3], 0, 0, 0); \
  } while (0)

  // phase: {ds_read 2 A-frags (+4 B-frags in ph0); stage 1 sweep} ->
  //        lgkm(0) gate (bounds live ranges - R6 lesson) -> 8 MFMA
#define PHASE(AB, MI0, MI1, READB, BB, SGC, SS, SLB) do { \
    if (READB) { \
      bfr[0] = LDB(BB, 0); bfr[1] = LDB(BB, 1); \
      bfr[2] = LDB(BB, 2); bfr[3] = LDB(BB, 3); \
    } \
    v4i a0 = LDA(AB, MI0); \
    v4i a1 = LDA(AB, MI1); \
    STAGE(SGC, SS, SLB); \
    __builtin_amdgcn_sched_barrier(0); \
    asm volatile("s_waitcnt lgkmcnt(0)" ::: "memory"); \
    __builtin_amdgcn_sched_barrier(0); \
    __builtin_amdgcn_s_setprio(1); \
    MFMA8(MI0, MI1, a0, a1); \
    __builtin_amdgcn_s_setprio(0); \
  } while (0)

#define TILEGATE do { \
    __builtin_amdgcn_sched_barrier(0); \
    asm volatile("s_waitcnt vmcnt(2)" ::: "memory"); \
    __builtin_amdgcn_s_barrier(); \
    __builtin_amdgcn_sched_barrier(0); \
  } while (0)

  // one K-tile: 4 phases; stages (positional): B(t+1)s0, B(t+1)s1,
  // A(t+2)s0, A(t+2)s1 -> tile-end vmcnt(2) leaves A(t+2) in flight.
#define KTILE(AB, BB, BBN, ASB, TT) do { \
    PHASE(AB, 0, 1, 1, BB, GBC((TT) + 1), 0, BBN); \
    PHASE(AB, 2, 3, 0, BB, GBC((TT) + 1), 1, BBN); \
    PHASE(AB, 4, 5, 0, BB, GAC((TT) + 2), 0, ASB); \
    PHASE(AB, 6, 7, 0, BB, GAC((TT) + 2), 1, ASB); \
    TILEGATE; \
  } while (0)

  // prologue: B(0)->Bbuf0, A(0)->Abuf0, A(1)->Abuf1; vm2 leaves A(1) in flight
  STAGE(GBC(0), 0, 49152);
  STAGE(GBC(0), 1, 49152);
  STAGE(GAC(0), 0, 0);
  STAGE(GAC(0), 1, 0);
  STAGE(GAC(1), 0, 16384);
  STAGE(GAC(1), 1, 16384);
  asm volatile("s_waitcnt vmcnt(2)" ::: "memory");
  __builtin_amdgcn_s_barrier();
  __builtin_amdgcn_sched_barrier(0);

  int aC = 0, aN = 16384, aS = 32768;

#pragma unroll 1
  for (int t = 0; t < NKT; t += 2) {
    // tile t: A in aC, B in Bbuf0; stage B(t+1)->Bbuf1, A(t+2)->aS
    KTILE(aC, 49152, 65536, aS, t);
    // tile t+1: A in aN, B in Bbuf1; stage B(t+2)->Bbuf0, A(t+3)->aC
    KTILE(aN, 65536, 49152, aC, t + 1);
    int tmp = aC; aC = aS; aS = aN; aN = tmp;
  }

  // epilogue: out = acc_i32 * scales[row] / (9*alpha)
  const float inv9a = 1.0f / (9.0f * alpha);
#pragma unroll
  for (int mi = 0; mi < 8; ++mi) {
    int rbase = m0 + (mi >> 2) * 128 + wm * 64 + (mi & 3) * 16 + (lane >> 4) * 4;
    float s0 = scales[rbase + 0] * inv9a;
    float s1 = scales[rbase + 1] * inv9a;
    float s2 = scales[rbase + 2] * inv9a;
    float s3 = scales[rbase + 3] * inv9a;
#pragma unroll
    for (int nj = 0; nj < 4; ++nj) {
      int col = n0 + (nj >> 1) * 128 + wn * 32 + (nj & 1) * 16 + (lane & 15);
      out[(size_t)(rbase + 0) * NDIM + col] = (float)acc[mi][nj][0] * s0;
      out[(size_t)(rbase + 1) * NDIM + col] = (float)acc[mi][nj][1] * s1;
      out[(size_t)(rbase + 2) * NDIM + col] = (float)acc[mi][nj][2] * s2;
      out[(size_t)(rbase + 3) * NDIM + col] = (float)acc[mi][nj][3] * s3;
    }
  }
#undef KTILE
#undef TILEGATE
#undef PHASE
#undef MFMA8
#undef STAGE
#undef GAC
#undef GBC
#undef LDA
#undef LDB
#undef AROW
#undef BROW
}

// ---------- fallback (ws too small): fp32 tiled GEMM, quant on the fly ----------

__global__ void fb_gemm_kernel(const float* __restrict__ X, const float* __restrict__ W,
                               const float* __restrict__ pAlpha, float* __restrict__ out) {
  __shared__ float As[64][17];
  __shared__ float Ws[64][17];
  const float alpha = pAlpha[0];
  const float scale = 1.0f / (9.0f * alpha);
  const int bm = blockIdx.x >> 6, bn = blockIdx.x & 63;
  const int t = threadIdx.x;
  const int tx = t & 15, ty = t >> 4;
  float acc[4][4] = {};
  for (int k0 = 0; k0 < KDIM; k0 += 16) {
    int r = t >> 2;
#pragma unroll
    for (int i = 0; i < 4; ++i) {
      int c = (t & 3) * 4 + i;
      As[r][c] = X[(size_t)(bm * 64 + r) * KDIM + k0 + c];
      float w = W[(size_t)(bn * 64 + r) * KDIM + k0 + c];
      Ws[r][c] = quant_wint(w, alpha) * scale;
    }
    __syncthreads();
#pragma unroll
    for (int kk = 0; kk < 16; ++kk)
#pragma unroll
      for (int i = 0; i < 4; ++i)
#pragma unroll
        for (int j = 0; j < 4; ++j)
          acc[i][j] += As[ty * 4 + i][kk] * Ws[tx * 4 + j][kk];
    __syncthreads();
  }
#pragma unroll
  for (int i = 0; i < 4; ++i)
#pragma unroll
    for (int j = 0; j < 4; ++j)
      out[(size_t)(bm * 64 + ty * 4 + i) * NDIM + bn * 64 + tx * 4 + j] = acc[i][j];
}

// ---------- launch ----------

extern "C" void kernel_launch(void* const* d_in, const int* in_sizes, int n_in,
                              void* d_out, int out_size, void* d_ws, size_t ws_size,
                              hipStream_t stream) {
  const float* x = (const float*)d_in[0];       // [16384,4096]
  const float* w = (const float*)d_in[1];       // [4096,4096]
  const float* alpha = (const float*)d_in[2];   // scalar
  float* out = (float*)d_out;

  const size_t XQ_BYTES = (size_t)MDIM * KDIM;              // 67.1 MB
  const size_t WQ_BYTES = (size_t)NDIM * KDIM;              // 16.8 MB
  const size_t SC_BYTES = (size_t)MDIM * 4;                 // 64 KB
  const size_t NEED = XQ_BYTES + WQ_BYTES + SC_BYTES;       // ~84 MB

  if (ws_size >= NEED) {
    s8* Xq = (s8*)d_ws;
    s8* Wq = (s8*)((char*)d_ws + XQ_BYTES);
    float* scales = (float*)((char*)d_ws + XQ_BYTES + WQ_BYTES);
    quant_x_kernel<<<MDIM, 256, 0, stream>>>((const float4*)x, Xq, scales);
    quant_w8_kernel<<<NDIM, 256, 0, stream>>>((const float4*)w, alpha, Wq);
    qgemm_kernel<<<(MDIM / BM) * (NDIM / BN), 512, 0, stream>>>(
        Xq, Wq, scales, alpha, out);
  } else {
    fb_gemm_kernel<<<(MDIM / 64) * (NDIM / 64), 256, 0, stream>>>(x, w, alpha, out);
  }
}